// Round 1
// baseline (879.398 us; speedup 1.0000x reference)
//
#include <hip/hip_runtime.h>
#include <math.h>

#define SEQ   2048
#define HID   1024
#define NHEAD 16
#define HDIM  64
#define NEXP  8
#define IDIM  4096
#define CAPE  1024
#define QKVW  3072

typedef __bf16    bf16x8 __attribute__((ext_vector_type(8)));
typedef __bf16    bf16x4 __attribute__((ext_vector_type(4)));
typedef _Float16  f16x8  __attribute__((ext_vector_type(8)));
typedef _Float16  f16x4  __attribute__((ext_vector_type(4)));
typedef float     f32x4  __attribute__((ext_vector_type(4)));

__device__ __forceinline__ void gld16(const void* g, void* l) {
  __builtin_amdgcn_global_load_lds((const __attribute__((address_space(1))) void*)g,
                                   (__attribute__((address_space(3))) void*)l, 16, 0, 0);
}

__device__ __forceinline__ bf16x8 cvt_bf8(const float4 a, const float4 b) {
  bf16x8 o;
  o[0] = (__bf16)a.x; o[1] = (__bf16)a.y; o[2] = (__bf16)a.z; o[3] = (__bf16)a.w;
  o[4] = (__bf16)b.x; o[5] = (__bf16)b.y; o[6] = (__bf16)b.z; o[7] = (__bf16)b.w;
  return o;
}

// ---------------- RMSNorm: fp32 out (opt), bf16 out (opt), f16 hi/lo out (opt) ----------------
__global__ __launch_bounds__(256) void k_rmsnorm(const float* __restrict__ x,
                                                 const float* __restrict__ w,
                                                 float* __restrict__ out,
                                                 __bf16* __restrict__ out_bf,
                                                 _Float16* __restrict__ out_h,
                                                 _Float16* __restrict__ out_l) {
  const int row = blockIdx.x, t = threadIdx.x;
  float4 v = ((const float4*)(x + (size_t)row * HID))[t];
  float ss = v.x*v.x + v.y*v.y + v.z*v.z + v.w*v.w;
  #pragma unroll
  for (int off = 32; off; off >>= 1) ss += __shfl_down(ss, off);
  __shared__ float red[4];
  if ((t & 63) == 0) red[t >> 6] = ss;
  __syncthreads();
  const float inv = rsqrtf((red[0] + red[1] + red[2] + red[3]) * (1.0f / HID) + 1e-6f);
  float4 wv = ((const float4*)w)[t];
  float4 o = make_float4(v.x*inv*wv.x, v.y*inv*wv.y, v.z*inv*wv.z, v.w*inv*wv.w);
  if (out) ((float4*)(out + (size_t)row * HID))[t] = o;
  if (out_bf) {
    bf16x4 ob; ob[0] = (__bf16)o.x; ob[1] = (__bf16)o.y; ob[2] = (__bf16)o.z; ob[3] = (__bf16)o.w;
    *(bf16x4*)(out_bf + (size_t)row * HID + t * 4) = ob;
  }
  if (out_h) {
    f16x4 oh, ol;
    const float e0 = o.x, e1 = o.y, e2 = o.z, e3 = o.w;
    oh[0] = (_Float16)e0; ol[0] = (_Float16)(e0 - (float)oh[0]);
    oh[1] = (_Float16)e1; ol[1] = (_Float16)(e1 - (float)oh[1]);
    oh[2] = (_Float16)e2; ol[2] = (_Float16)(e2 - (float)oh[2]);
    oh[3] = (_Float16)e3; ol[3] = (_Float16)(e3 - (float)oh[3]);
    *(f16x4*)(out_h + (size_t)row * HID + t * 4) = oh;
    *(f16x4*)(out_l + (size_t)row * HID + t * 4) = ol;
  }
}

// ---------------- fp32 -> f16 hi/lo split ----------------
__global__ __launch_bounds__(256) void k_split_f16(const float* __restrict__ in,
                                                   _Float16* __restrict__ oh,
                                                   _Float16* __restrict__ ol,
                                                   long n8) {
  const long i = ((long)blockIdx.x * 256 + threadIdx.x);
  if (i >= n8) return;
  const float4 a = *(const float4*)(in + i * 8);
  const float4 b = *(const float4*)(in + i * 8 + 4);
  float e[8] = {a.x, a.y, a.z, a.w, b.x, b.y, b.z, b.w};
  f16x8 h, l;
  #pragma unroll
  for (int j = 0; j < 8; ++j) {
    h[j] = (_Float16)e[j];
    l[j] = (_Float16)(e[j] - (float)h[j]);
  }
  *(f16x8*)(oh + i * 8) = h;
  *(f16x8*)(ol + i * 8) = l;
}

// ---------------- split-f16 MFMA NT GEMM ----------------
__global__ __launch_bounds__(256, 2) void k_lin(const _Float16* __restrict__ Ah,
                                                const _Float16* __restrict__ Al,
                                                const _Float16* __restrict__ Bh,
                                                const _Float16* __restrict__ Bl,
                                                const float* __restrict__ res,
                                                float* __restrict__ C,
                                                int N, int Kd) {
  const int m0 = blockIdx.y * 128, n0 = blockIdx.x * 128;
  __shared__ __align__(16) _Float16 Ash[128 * 32];
  __shared__ __align__(16) _Float16 Asl[128 * 32];
  __shared__ __align__(16) _Float16 Bsh[128 * 32];
  __shared__ __align__(16) _Float16 Bsl[128 * 32];
  const int t = threadIdx.x, lane = t & 63, w = t >> 6;
  const int wr = w & 1, wc = w >> 1;
  const int sr = t >> 2, sk = (t & 3) * 8;
  const size_t a0 = (size_t)(m0 + sr) * Kd, a1 = (size_t)(m0 + 64 + sr) * Kd;
  const size_t b0 = (size_t)(n0 + sr) * Kd, b1 = (size_t)(n0 + 64 + sr) * Kd;
  f32x4 acc[4][4];
  #pragma unroll
  for (int i = 0; i < 4; ++i)
    #pragma unroll
    for (int j = 0; j < 4; ++j) acc[i][j] = (f32x4)(0.f);

  for (int kk = 0; kk < Kd; kk += 32) {
    gld16(Ah + a0 + kk + sk, Ash + w * 512);
    gld16(Ah + a1 + kk + sk, Ash + 2048 + w * 512);
    gld16(Al + a0 + kk + sk, Asl + w * 512);
    gld16(Al + a1 + kk + sk, Asl + 2048 + w * 512);
    gld16(Bh + b0 + kk + sk, Bsh + w * 512);
    gld16(Bh + b1 + kk + sk, Bsh + 2048 + w * 512);
    gld16(Bl + b0 + kk + sk, Bsl + w * 512);
    gld16(Bl + b1 + kk + sk, Bsl + 2048 + w * 512);
    __syncthreads();
    const int fo = (lane & 15) * 32 + (lane >> 4) * 8;
    f16x8 ah[4], al[4], bh[4], bl[4];
    #pragma unroll
    for (int i = 0; i < 4; ++i) {
      ah[i] = *(const f16x8*)&Ash[(wr * 64 + i * 16) * 32 + fo];
      al[i] = *(const f16x8*)&Asl[(wr * 64 + i * 16) * 32 + fo];
      bh[i] = *(const f16x8*)&Bsh[(wc * 64 + i * 16) * 32 + fo];
      bl[i] = *(const f16x8*)&Bsl[(wc * 64 + i * 16) * 32 + fo];
    }
    #pragma unroll
    for (int i = 0; i < 4; ++i)
      #pragma unroll
      for (int j = 0; j < 4; ++j) {
        acc[i][j] = __builtin_amdgcn_mfma_f32_16x16x32_f16(al[i], bh[j], acc[i][j], 0, 0, 0);
        acc[i][j] = __builtin_amdgcn_mfma_f32_16x16x32_f16(ah[i], bl[j], acc[i][j], 0, 0, 0);
        acc[i][j] = __builtin_amdgcn_mfma_f32_16x16x32_f16(ah[i], bh[j], acc[i][j], 0, 0, 0);
      }
    __syncthreads();
  }
  const int cb = lane & 15, rb = (lane >> 4) * 4;
  #pragma unroll
  for (int i = 0; i < 4; ++i)
    #pragma unroll
    for (int r = 0; r < 4; ++r) {
      const int rr = m0 + wr * 64 + i * 16 + rb + r;
      #pragma unroll
      for (int j = 0; j < 4; ++j) {
        const int cc = n0 + wc * 64 + j * 16 + cb;
        float v = acc[i][j][r];
        if (res) v += res[(size_t)rr * N + cc];
        C[(size_t)rr * N + cc] = v;
      }
    }
}

// ---------------- prep: RoPE + q-scale + f16 hi/lo split of Q,K; V transpose+split ----------------
__global__ __launch_bounds__(256) void k_prep(const float* __restrict__ qkv,
                                              _Float16* __restrict__ Qh, _Float16* __restrict__ Ql,
                                              _Float16* __restrict__ Kh, _Float16* __restrict__ Kl,
                                              _Float16* __restrict__ Vth, _Float16* __restrict__ Vtl) {
  const int h = blockIdx.x, s0 = blockIdx.y * 64;
  const int t = threadIdx.x;
  const int sl = t >> 2, qd = t & 3;
  const int s = s0 + sl;
  const float* base = qkv + (size_t)s * QKVW + h * HDIM;
  __shared__ float vt[64][65];

  {
    const float* vb = base + 2 * HID + qd * 16;
    #pragma unroll
    for (int c = 0; c < 4; ++c) {
      float4 v = *(const float4*)(vb + c * 4);
      vt[sl][qd * 16 + c * 4 + 0] = v.x;
      vt[sl][qd * 16 + c * 4 + 1] = v.y;
      vt[sl][qd * 16 + c * 4 + 2] = v.z;
      vt[sl][qd * 16 + c * 4 + 3] = v.w;
    }
  }

  const int d0 = qd * 8;
  const float LOG10000 = 9.210340371976184f;
  float cv[8], sv[8];
  #pragma unroll
  for (int i = 0; i < 8; ++i) {
    const float ang = (float)s * expf(-(float)(d0 + i) * (1.0f / 32.0f) * LOG10000);
    sincosf(ang, &sv[i], &cv[i]);
  }
  float qa[8], qb[8], ka[8], kb[8];
  {
    float4 x0 = *(const float4*)(base + d0), x1 = *(const float4*)(base + d0 + 4);
    float4 y0 = *(const float4*)(base + d0 + 32), y1 = *(const float4*)(base + d0 + 36);
    qa[0]=x0.x; qa[1]=x0.y; qa[2]=x0.z; qa[3]=x0.w; qa[4]=x1.x; qa[5]=x1.y; qa[6]=x1.z; qa[7]=x1.w;
    qb[0]=y0.x; qb[1]=y0.y; qb[2]=y0.z; qb[3]=y0.w; qb[4]=y1.x; qb[5]=y1.y; qb[6]=y1.z; qb[7]=y1.w;
    const float* kbase = base + HID;
    float4 z0 = *(const float4*)(kbase + d0), z1 = *(const float4*)(kbase + d0 + 4);
    float4 w0 = *(const float4*)(kbase + d0 + 32), w1 = *(const float4*)(kbase + d0 + 36);
    ka[0]=z0.x; ka[1]=z0.y; ka[2]=z0.z; ka[3]=z0.w; ka[4]=z1.x; ka[5]=z1.y; ka[6]=z1.z; ka[7]=z1.w;
    kb[0]=w0.x; kb[1]=w0.y; kb[2]=w0.z; kb[3]=w0.w; kb[4]=w1.x; kb[5]=w1.y; kb[6]=w1.z; kb[7]=w1.w;
  }
  f16x8 qh_a, ql_a, qh_b, ql_b, kh_a, kl_a, kh_b, kl_b;
  #pragma unroll
  for (int i = 0; i < 8; ++i) {
    const float q1 = (qa[i] * cv[i] - qb[i] * sv[i]) * 0.125f;
    const float q2 = (qb[i] * cv[i] + qa[i] * sv[i]) * 0.125f;
    const float k1 = ka[i] * cv[i] - kb[i] * sv[i];
    const float k2 = kb[i] * cv[i] + ka[i] * sv[i];
    qh_a[i] = (_Float16)q1; ql_a[i] = (_Float16)(q1 - (float)qh_a[i]);
    qh_b[i] = (_Float16)q2; ql_b[i] = (_Float16)(q2 - (float)qh_b[i]);
    kh_a[i] = (_Float16)k1; kl_a[i] = (_Float16)(k1 - (float)kh_a[i]);
    kh_b[i] = (_Float16)k2; kl_b[i] = (_Float16)(k2 - (float)kh_b[i]);
  }
  const size_t qko = ((size_t)h * SEQ + s) * 64;
  *(f16x8*)(Qh + qko + d0) = qh_a;      *(f16x8*)(Qh + qko + d0 + 32) = qh_b;
  *(f16x8*)(Ql + qko + d0) = ql_a;      *(f16x8*)(Ql + qko + d0 + 32) = ql_b;
  *(f16x8*)(Kh + qko + d0) = kh_a;      *(f16x8*)(Kh + qko + d0 + 32) = kh_b;
  *(f16x8*)(Kl + qko + d0) = kl_a;      *(f16x8*)(Kl + qko + d0 + 32) = kl_b;

  __syncthreads();
  {
    const int d = t >> 2, sc = (t & 3) * 16;
    f16x8 vh0, vl0, vh1, vl1;
    #pragma unroll
    for (int j = 0; j < 8; ++j) {
      const float v = vt[sc + j][d];
      vh0[j] = (_Float16)v; vl0[j] = (_Float16)(v - (float)vh0[j]);
    }
    #pragma unroll
    for (int j = 0; j < 8; ++j) {
      const float v = vt[sc + 8 + j][d];
      vh1[j] = (_Float16)v; vl1[j] = (_Float16)(v - (float)vh1[j]);
    }
    const size_t vo = ((size_t)h * HDIM + d) * SEQ + s0 + sc;
    *(f16x8*)(Vth + vo) = vh0; *(f16x8*)(Vth + vo + 8) = vh1;
    *(f16x8*)(Vtl + vo) = vl0; *(f16x8*)(Vtl + vo + 8) = vl1;
  }
}

// ---------------- MFMA flash attention, split-f16 (fp32-equivalent) ----------------
__global__ __launch_bounds__(256) void k_attn2(
    const _Float16* __restrict__ Qh, const _Float16* __restrict__ Ql,
    const _Float16* __restrict__ Kh, const _Float16* __restrict__ Kl,
    const _Float16* __restrict__ Vth, const _Float16* __restrict__ Vtl,
    _Float16* __restrict__ attn_h, _Float16* __restrict__ attn_l) {
  const int h = blockIdx.x;
  const int qt = (int)gridDim.y - 1 - (int)blockIdx.y;   // heavy tiles first
  const int t = threadIdx.x, lane = t & 63, w = t >> 6;
  const int m_ = lane & 15, quad = lane >> 4;

  __shared__ __align__(16) _Float16 Ksh[2][64][32];
  __shared__ __align__(16) _Float16 Ksl[2][64][32];
  __shared__ __align__(16) _Float16 Vsh[4][64][16];
  __shared__ __align__(16) _Float16 Vsl[4][64][16];
  __shared__ __align__(16) _Float16 Ph[4][16][72];
  __shared__ __align__(16) _Float16 Pl[4][16][72];

  const int q0 = qt * 64 + w * 16;
  const _Float16* qbh = Qh + ((size_t)h * SEQ + q0 + m_) * 64 + quad * 8;
  const _Float16* qbl = Ql + ((size_t)h * SEQ + q0 + m_) * 64 + quad * 8;
  const f16x8 qh0 = *(const f16x8*)(qbh);
  const f16x8 qh1 = *(const f16x8*)(qbh + 32);
  const f16x8 ql0 = *(const f16x8*)(qbl);
  const f16x8 ql1 = *(const f16x8*)(qbl + 32);

  f32x4 o[4];
  #pragma unroll
  for (int nt = 0; nt < 4; ++nt) o[nt] = (f32x4)(0.f);
  float m_r[4] = {-1e30f, -1e30f, -1e30f, -1e30f};
  float l_r[4] = {0.f, 0.f, 0.f, 0.f};

  for (int kt = 0; kt <= qt; ++kt) {
    if (w == 0) {
      #pragma unroll
      for (int c = 0; c < 2; ++c)
        #pragma unroll
        for (int kb = 0; kb < 4; ++kb)
          gld16(Kh + ((size_t)h * SEQ + kt * 64 + kb * 16 + (lane >> 2)) * 64 + c * 32 + (lane & 3) * 8,
                &Ksh[c][kb * 16][0]);
    } else if (w == 1) {
      #pragma unroll
      for (int c = 0; c < 2; ++c)
        #pragma unroll
        for (int kb = 0; kb < 4; ++kb)
          gld16(Kl + ((size_t)h * SEQ + kt * 64 + kb * 16 + (lane >> 2)) * 64 + c * 32 + (lane & 3) * 8,
                &Ksl[c][kb * 16][0]);
    } else if (w == 2) {
      #pragma unroll
      for (int g = 0; g < 4; ++g)
        #pragma unroll
        for (int hd = 0; hd < 2; ++hd)
          gld16(Vth + ((size_t)h * HDIM + hd * 32 + (lane >> 1)) * SEQ + kt * 64 + g * 16 + (lane & 1) * 8,
                &Vsh[g][hd * 32][0]);
    } else {
      #pragma unroll
      for (int g = 0; g < 4; ++g)
        #pragma unroll
        for (int hd = 0; hd < 2; ++hd)
          gld16(Vtl + ((size_t)h * HDIM + hd * 32 + (lane >> 1)) * SEQ + kt * 64 + g * 16 + (lane & 1) * 8,
                &Vsl[g][hd * 32][0]);
    }
    __syncthreads();

    // ---- S = Q K^T ----
    f32x4 s4[4];
    #pragma unroll
    for (int nt = 0; nt < 4; ++nt) s4[nt] = (f32x4)(0.f);
    __builtin_amdgcn_s_setprio(1);
    #pragma unroll
    for (int c = 0; c < 2; ++c) {
      const f16x8 qhc = c ? qh1 : qh0;
      const f16x8 qlc = c ? ql1 : ql0;
      #pragma unroll
      for (int nt = 0; nt < 4; ++nt) {
        const f16x8 kh8 = *(const f16x8*)&Ksh[c][nt * 16 + m_][quad * 8];
        const f16x8 kl8 = *(const f16x8*)&Ksl[c][nt * 16 + m_][quad * 8];
        s4[nt] = __builtin_amdgcn_mfma_f32_16x16x32_f16(qlc, kh8, s4[nt], 0, 0, 0);
        s4[nt] = __builtin_amdgcn_mfma_f32_16x16x32_f16(qhc, kl8, s4[nt], 0, 0, 0);
        s4[nt] = __builtin_amdgcn_mfma_f32_16x16x32_f16(qhc, kh8, s4[nt], 0, 0, 0);
      }
    }
    __builtin_amdgcn_s_setprio(0);
    if (kt == qt) {
      #pragma unroll
      for (int nt = 0; nt < 4; ++nt)
        #pragma unroll
        for (int r = 0; r < 4; ++r)
          if (nt * 16 + m_ > w * 16 + quad * 4 + r) s4[nt][r] = -1e30f;
    }
    float mx[4];
    #pragma unroll
    for (int r = 0; r < 4; ++r)
      mx[r] = fmaxf(fmaxf(s4[0][r], s4[1][r]), fmaxf(s4[2][r], s4[3][r]));
    #pragma unroll
    for (int msk = 1; msk < 16; msk <<= 1)
      #pragma unroll
      for (int r = 0; r < 4; ++r) mx[r] = fmaxf(mx[r], __shfl_xor(mx[r], msk));
    float al[4];
    #pragma unroll
    for (int r = 0; r < 4; ++r) {
      const float mn = fmaxf(m_r[r], mx[r]);
      al[r] = expf(m_r[r] - mn);
      m_r[r] = mn;
    }
    float rs[4] = {0.f, 0.f, 0.f, 0.f};
    #pragma unroll
    for (int nt = 0; nt < 4; ++nt) {
      #pragma unroll
      for (int r = 0; r < 4; ++r) {
        const float p = expf(s4[nt][r] - m_r[r]);
        rs[r] += p;
        const _Float16 ph = (_Float16)p;
        Ph[w][quad * 4 + r][nt * 16 + m_] = ph;
        Pl[w][quad * 4 + r][nt * 16 + m_] = (_Float16)(p - (float)ph);
      }
    }
    #pragma unroll
    for (int msk = 1; msk < 16; msk <<= 1)
      #pragma unroll
      for (int r = 0; r < 4; ++r) rs[r] += __shfl_xor(rs[r], msk);
    #pragma unroll
    for (int r = 0; r < 4; ++r) l_r[r] = l_r[r] * al[r] + rs[r];
    #pragma unroll
    for (int nt = 0; nt < 4; ++nt)
      #pragma unroll
      for (int r = 0; r < 4; ++r) o[nt][r] *= al[r];

    // ---- O += P V ----
    __builtin_amdgcn_s_setprio(1);
    #pragma unroll
    for (int c = 0; c < 2; ++c) {
      const f16x8 pah = *(const f16x8*)&Ph[w][m_][c * 32 + quad * 8];
      const f16x8 pal = *(const f16x8*)&Pl[w][m_][c * 32 + quad * 8];
      #pragma unroll
      for (int nt = 0; nt < 4; ++nt) {
        const f16x8 vh8 = *(const f16x8*)&Vsh[c * 2 + (quad >> 1)][nt * 16 + m_][(quad & 1) * 8];
        const f16x8 vl8 = *(const f16x8*)&Vsl[c * 2 + (quad >> 1)][nt * 16 + m_][(quad & 1) * 8];
        o[nt] = __builtin_amdgcn_mfma_f32_16x16x32_f16(pal, vh8, o[nt], 0, 0, 0);
        o[nt] = __builtin_amdgcn_mfma_f32_16x16x32_f16(pah, vl8, o[nt], 0, 0, 0);
        o[nt] = __builtin_amdgcn_mfma_f32_16x16x32_f16(pah, vh8, o[nt], 0, 0, 0);
      }
    }
    __builtin_amdgcn_s_setprio(0);
    __syncthreads();
  }

  float inv[4];
  #pragma unroll
  for (int r = 0; r < 4; ++r) inv[r] = 1.0f / l_r[r];
  #pragma unroll
  for (int nt = 0; nt < 4; ++nt)
    #pragma unroll
    for (int r = 0; r < 4; ++r) {
      const float v = o[nt][r] * inv[r];
      const _Float16 hi = (_Float16)v;
      const size_t idx = ((size_t)(q0 + quad * 4 + r)) * HID + h * HDIM + nt * 16 + m_;
      attn_h[idx] = hi;
      attn_l[idx] = (_Float16)(v - (float)hi);
    }
}

// ---------------- router ----------------
__global__ __launch_bounds__(64) void k_router(const float* __restrict__ xn2,
                                               const float* __restrict__ rw,
                                               int* __restrict__ tidx,
                                               float* __restrict__ tw) {
  const int n = blockIdx.x, lane = threadIdx.x;
  float lg[8] = {0.f,0.f,0.f,0.f,0.f,0.f,0.f,0.f};
  #pragma unroll
  for (int i = 0; i < 4; ++i) {
    float4 xv = ((const float4*)(xn2 + (size_t)n * HID))[lane + 64 * i];
    #pragma unroll
    for (int e = 0; e < 8; ++e) {
      float4 wv = ((const float4*)(rw + (size_t)e * HID))[lane + 64 * i];
      lg[e] += xv.x*wv.x + xv.y*wv.y + xv.z*wv.z + xv.w*wv.w;
    }
  }
  #pragma unroll
  for (int e = 0; e < 8; ++e) {
    #pragma unroll
    for (int off = 32; off; off >>= 1) lg[e] += __shfl_xor(lg[e], off);
  }
  if (lane == 0) {
    int e1 = 0; float l1 = lg[0];
    #pragma unroll
    for (int e = 1; e < 8; ++e) if (lg[e] > l1) { l1 = lg[e]; e1 = e; }
    int e2 = -1; float l2 = -INFINITY;
    #pragma unroll
    for (int e = 0; e < 8; ++e) if (e != e1 && lg[e] > l2) { l2 = lg[e]; e2 = e; }
    const float w1 = 1.0f / (1.0f + expf(l2 - l1));
    tidx[n * 2] = e1; tidx[n * 2 + 1] = e2;
    tw[n * 2] = w1;  tw[n * 2 + 1] = 1.0f - w1;
  }
}

// ---------------- capacity scan + aux loss ----------------
__global__ __launch_bounds__(512) void k_scan(const int* __restrict__ tidx,
                                              int* __restrict__ slotk,
                                              int* __restrict__ perm,
                                              int* __restrict__ counts,
                                              float* __restrict__ aux_out) {
  const int t = threadIdx.x;
  const int e = t >> 6, lane = t & 63;
  __shared__ int cls[8];
  int offset = 0;
  for (int chunk = 0; chunk < SEQ / 64; ++chunk) {
    const int n = chunk * 64 + lane;
    const int i0 = tidx[n * 2], i1 = tidx[n * 2 + 1];
    const bool bit = (i0 == e) || (i1 == e);
    const unsigned long long mask = __ballot(bit);
    const int pos = offset + __popcll(mask & ((1ull << lane) - 1ull));
    if (bit) {
      const int kk = (i0 == e) ? 0 : 1;
      slotk[n * 2 + kk] = pos;
      if (pos < CAPE) perm[e * CAPE + pos] = n;
    }
    offset += __popcll(mask);
  }
  if (lane == 0) { counts[e] = offset; cls[e] = offset; }
  __syncthreads();
  if (t == 0) {
    float mean = 0.f;
    for (int i = 0; i < 8; ++i) mean += (float)cls[i];
    mean /= (8.0f * (float)SEQ);
    float var = 0.f;
    for (int i = 0; i < 8; ++i) {
      const float f = (float)cls[i] / (float)SEQ;
      var += (f - mean) * (f - mean);
    }
    var /= 7.0f;
    aux_out[0] = var * 8.0f;
  }
}

// ---------------- MoE gate/up: fused fp32->bf16 weight staging, 2-phase dbuf ----------------
__global__ __launch_bounds__(256, 2) void k_moe_gu(const __bf16* __restrict__ X,
                                                   const float* __restrict__ Wg,
                                                   const float* __restrict__ Wu,
                                                   const int* __restrict__ perm,
                                                   const int* __restrict__ counts,
                                                   __bf16* __restrict__ act) {
  const int e = blockIdx.z;
  const int rows = min(counts[e], CAPE);
  const int m0 = blockIdx.y * 128;
  if (m0 >= rows) return;
  const int n0 = blockIdx.x * 128;
  __shared__ __align__(16) __bf16 As[2][128 * 32];
  __shared__ __align__(16) __bf16 Bgs[2][128 * 32];
  __shared__ __align__(16) __bf16 Bus[2][128 * 32];
  const int t = threadIdx.x;
  const int lane = t & 63, w = t >> 6;
  const int wr = w & 1, wc = w >> 1;
  const int sr = t >> 2;
  const int sk = (t & 3) * 8;
  const int gr0 = m0 + sr, gr1 = m0 + 64 + sr;
  const size_t arow0 = (size_t)((gr0 < rows) ? perm[e * CAPE + gr0] : 0) * HID;
  const size_t arow1 = (size_t)((gr1 < rows) ? perm[e * CAPE + gr1] : 0) * HID;
  const float* gB = Wg + (size_t)e * IDIM * HID;
  const float* uB = Wu + (size_t)e * IDIM * HID;
  const size_t brow0 = (size_t)(n0 + sr) * HID + sk;
  const size_t brow1 = (size_t)(n0 + 64 + sr) * HID + sk;
  const int wb  = sr * 32 + sk;          // ds-write offset for row sr
  const int wb2 = (64 + sr) * 32 + sk;   // row sr+64
  f32x4 accg[4][4], accu[4][4];
  #pragma unroll
  for (int i = 0; i < 4; ++i)
    #pragma unroll
    for (int j = 0; j < 4; ++j) { accg[i][j] = (f32x4)(0.f); accu[i][j] = (f32x4)(0.f); }

  // prologue: stage K-tile 0
  {
    gld16(X + arow0 + sk, &As[0][w * 512]);
    gld16(X + arow1 + sk, &As[0][2048 + w * 512]);
    const float4 g0 = *(const float4*)(gB + brow0);
    const float4 g1 = *(const float4*)(gB + brow0 + 4);
    const float4 g2 = *(const float4*)(gB + brow1);
    const float4 g3 = *(const float4*)(gB + brow1 + 4);
    const float4 u0 = *(const float4*)(uB + brow0);
    const float4 u1 = *(const float4*)(uB + brow0 + 4);
    const float4 u2 = *(const float4*)(uB + brow1);
    const float4 u3 = *(const float4*)(uB + brow1 + 4);
    *(bf16x8*)&Bgs[0][wb]  = cvt_bf8(g0, g1);
    *(bf16x8*)&Bgs[0][wb2] = cvt_bf8(g2, g3);
    *(bf16x8*)&Bus[0][wb]  = cvt_bf8(u0, u1);
    *(bf16x8*)&Bus[0][wb2] = cvt_bf8(u2, u3);
  }
  __syncthreads();

  int cur = 0;
  for (int kk = 0; kk < HID; kk += 32) {
    const int nxt = cur ^ 1;
    const bool pf = (kk + 32) < HID;
    float4 g0, g1, g2, g3, u0, u1, u2, u3;
    if (pf) {
      // T14: issue next-tile loads before current-tile compute
      gld16(X + arow0 + kk + 32 + sk, &As[nxt][w * 512]);
      gld16(X + arow1 + kk + 32 + sk, &As[nxt][2048 + w * 512]);
      g0 = *(const float4*)(gB + brow0 + kk + 32);
      g1 = *(const float4*)(gB + brow0 + kk + 36);
      g2 = *(const float4*)(gB + brow1 + kk + 32);
      g3 = *(const float4*)(gB + brow1 + kk + 36);
      u0 = *(const float4*)(uB + brow0 + kk + 32);
      u1 = *(const float4*)(uB + brow0 + kk + 36);
      u2 = *(const float4*)(uB + brow1 + kk + 32);
      u3 = *(const float4*)(uB + brow1 + kk + 36);
    }
    const int fo = (lane & 15) * 32 + (lane >> 4) * 8;
    bf16x8 a[4], bg[4], bu[4];
    #pragma unroll
    for (int i = 0; i < 4; ++i) {
      a[i]  = *(const bf16x8*)&As[cur][(wr * 64 + i * 16) * 32 + fo];
      bg[i] = *(const bf16x8*)&Bgs[cur][(wc * 64 + i * 16) * 32 + fo];
      bu[i] = *(const bf16x8*)&Bus[cur][(wc * 64 + i * 16) * 32 + fo];
    }
    #pragma unroll
    for (int i = 0; i < 4; ++i)
      #pragma unroll
      for (int j = 0; j < 4; ++j) {
        accg[i][j] = __builtin_amdgcn_mfma_f32_16x16x32_bf16(a[i], bg[j], accg[i][j], 0, 0, 0);
        accu[i][j] = __builtin_amdgcn_mfma_f32_16x16x32_bf16(a[i], bu[j], accu[i][j], 0, 0, 0);
      }
    if (pf) {
      // write-late: convert + ds_write after MFMAs (loads have drained under compute)
      *(bf16x8*)&Bgs[nxt][wb]  = cvt_bf8(g0, g1);
      *(bf16x8*)&Bgs[nxt][wb2] = cvt_bf8(g2, g3);
      *(bf16x8*)&Bus[nxt][wb]  = cvt_bf8(u0, u1);
      *(bf16x8*)&Bus[nxt][wb2] = cvt_bf8(u2, u3);
    }
    __syncthreads();
    cur = nxt;
  }
  const int cb = lane & 15, rb = (lane >> 4) * 4;
  #pragma unroll
  for (int i = 0; i < 4; ++i)
    #pragma unroll
    for (int r = 0; r < 4; ++r) {
      const int rr = m0 + wr * 64 + i * 16 + rb + r;
      if (rr < rows) {
        #pragma unroll
        for (int j = 0; j < 4; ++j) {
          const float g = accg[i][j][r], u = accu[i][j][r];
          const float v = g / (1.f + expf(-g)) * u;
          act[((size_t)e * CAPE + rr) * IDIM + n0 + wc * 64 + j * 16 + cb] = (__bf16)v;
        }
      }
    }
}

// ---------------- MoE down: fused fp32->bf16 weight staging, 2-phase dbuf ----------------
__global__ __launch_bounds__(256, 2) void k_moe_down(const __bf16* __restrict__ act,
                                                     const float* __restrict__ Wd,
                                                     const int* __restrict__ counts,
                                                     float* __restrict__ y) {
  const int e = blockIdx.z;
  const int rows = min(counts[e], CAPE);
  const int m0 = blockIdx.y * 128;
  if (m0 >= rows) return;
  const int n0 = blockIdx.x * 128;
  __shared__ __align__(16) __bf16 As[2][128 * 32];
  __shared__ __align__(16) __bf16 Bs[2][128 * 32];
  const int t = threadIdx.x;
  const int lane = t & 63, w = t >> 6;
  const int wr = w & 1, wc = w >> 1;
  const int sr = t >> 2;
  const int sk = (t & 3) * 8;
  const __bf16* Ab = act + ((size_t)e * CAPE) * IDIM;
  const float* Bb = Wd + (size_t)e * HID * IDIM;
  const size_t arow0 = (size_t)(m0 + sr) * IDIM + sk, arow1 = (size_t)(m0 + 64 + sr) * IDIM + sk;
  const size_t brow0 = (size_t)(n0 + sr) * IDIM + sk, brow1 = (size_t)(n0 + 64 + sr) * IDIM + sk;
  const int wb  = sr * 32 + sk;
  const int wb2 = (64 + sr) * 32 + sk;
  f32x4 acc[4][4];
  #pragma unroll
  for (int i = 0; i < 4; ++i)
    #pragma unroll
    for (int j = 0; j < 4; ++j) acc[i][j] = (f32x4)(0.f);

  // prologue
  {
    gld16(Ab + arow0, &As[0][w * 512]);
    gld16(Ab + arow1, &As[0][2048 + w * 512]);
    const float4 b0 = *(const float4*)(Bb + brow0);
    const float4 b1 = *(const float4*)(Bb + brow0 + 4);
    const float4 b2 = *(const float4*)(Bb + brow1);
    const float4 b3 = *(const float4*)(Bb + brow1 + 4);
    *(bf16x8*)&Bs[0][wb]  = cvt_bf8(b0, b1);
    *(bf16x8*)&Bs[0][wb2] = cvt_bf8(b2, b3);
  }
  __syncthreads();

  int cur = 0;
  for (int kk = 0; kk < IDIM; kk += 32) {
    const int nxt = cur ^ 1;
    const bool pf = (kk + 32) < IDIM;
    float4 b0, b1, b2, b3;
    if (pf) {
      gld16(Ab + arow0 + kk + 32, &As[nxt][w * 512]);
      gld16(Ab + arow1 + kk + 32, &As[nxt][2048 + w * 512]);
      b0 = *(const float4*)(Bb + brow0 + kk + 32);
      b1 = *(const float4*)(Bb + brow0 + kk + 36);
      b2 = *(const float4*)(Bb + brow1 + kk + 32);
      b3 = *(const float4*)(Bb + brow1 + kk + 36);
    }
    const int fo = (lane & 15) * 32 + (lane >> 4) * 8;
    bf16x8 a[4], b[4];
    #pragma unroll
    for (int i = 0; i < 4; ++i) {
      a[i] = *(const bf16x8*)&As[cur][(wr * 64 + i * 16) * 32 + fo];
      b[i] = *(const bf16x8*)&Bs[cur][(wc * 64 + i * 16) * 32 + fo];
    }
    #pragma unroll
    for (int i = 0; i < 4; ++i)
      #pragma unroll
      for (int j = 0; j < 4; ++j)
        acc[i][j] = __builtin_amdgcn_mfma_f32_16x16x32_bf16(a[i], b[j], acc[i][j], 0, 0, 0);
    if (pf) {
      *(bf16x8*)&Bs[nxt][wb]  = cvt_bf8(b0, b1);
      *(bf16x8*)&Bs[nxt][wb2] = cvt_bf8(b2, b3);
    }
    __syncthreads();
    cur = nxt;
  }
  const int cb = lane & 15, rb = (lane >> 4) * 4;
  #pragma unroll
  for (int i = 0; i < 4; ++i)
    #pragma unroll
    for (int r = 0; r < 4; ++r) {
      const int rr = m0 + wr * 64 + i * 16 + rb + r;
      if (rr < rows) {
        #pragma unroll
        for (int j = 0; j < 4; ++j)
          y[((size_t)e * CAPE + rr) * HID + n0 + wc * 64 + j * 16 + cb] = acc[i][j][r];
      }
    }
}

// ---------------- combine ----------------
__global__ __launch_bounds__(256) void k_combine(const float* __restrict__ x1,
                                                 const float* __restrict__ y,
                                                 const int* __restrict__ tidx,
                                                 const float* __restrict__ tw,
                                                 const int* __restrict__ slotk,
                                                 float* __restrict__ out) {
  const int n = blockIdx.x, t = threadIdx.x;
  float4 acc = ((const float4*)(x1 + (size_t)n * HID))[t];
  #pragma unroll
  for (int k = 0; k < 2; ++k) {
    const int slot = slotk[n * 2 + k];
    if (slot < CAPE) {
      const int e = tidx[n * 2 + k];
      const float w = tw[n * 2 + k];
      float4 v = ((const float4*)(y + ((size_t)e * CAPE + slot) * HID))[t];
      acc.x += w * v.x; acc.y += w * v.y; acc.z += w * v.z; acc.w += w * v.w;
    }
  }
  ((float4*)(out + (size_t)n * HID))[t] = acc;
}

extern "C" void kernel_launch(void* const* d_in, const int* in_sizes, int n_in,
                              void* d_out, int out_size, void* d_ws, size_t ws_size,
                              hipStream_t stream) {
  const float* x     = (const float*)d_in[0];
  const float* anw   = (const float*)d_in[1];
  const float* qkv_w = (const float*)d_in[2];
  const float* o_w   = (const float*)d_in[3];
  const float* fnw   = (const float*)d_in[4];
  const float* rw    = (const float*)d_in[5];
  const float* wg    = (const float*)d_in[6];
  const float* wu    = (const float*)d_in[7];
  const float* wd    = (const float*)d_in[8];
  (void)in_sizes; (void)n_in; (void)out_size; (void)ws_size;
  float* out = (float*)d_out;

  float* ws = (float*)d_ws;
  size_t off = 0;
  float* qkv  = ws + off; off += (size_t)SEQ * QKVW;
  float* x1   = ws + off; off += (size_t)SEQ * HID;
  float* xn2  = ws + off; off += (size_t)SEQ * HID;
  float* ybuf = ws + off; off += (size_t)NEXP * CAPE * HID;
  float* tw   = ws + off; off += SEQ * 2;
  int* tidx   = (int*)(ws + off); off += SEQ * 2;
  int* slotk  = (int*)(ws + off); off += SEQ * 2;
  int* perm   = (int*)(ws + off); off += NEXP * CAPE;
  int* counts = (int*)(ws + off); off += 16;
  // 2-byte element region
  __bf16* bfbase = (__bf16*)(ws + off);
  size_t boff = 0;
  __bf16* xn2_bf = bfbase + boff; boff += (size_t)SEQ * HID;
  __bf16* act_bf = bfbase + boff; boff += (size_t)NEXP * CAPE * IDIM;
  _Float16* f16base = (_Float16*)(bfbase + boff);
  size_t foff = 0;
  _Float16* xn_h   = f16base + foff; foff += (size_t)SEQ * HID;
  _Float16* xn_l   = f16base + foff; foff += (size_t)SEQ * HID;
  _Float16* qkvw_h = f16base + foff; foff += (size_t)QKVW * HID;
  _Float16* qkvw_l = f16base + foff; foff += (size_t)QKVW * HID;
  _Float16* attn_h = f16base + foff; foff += (size_t)SEQ * HID;
  _Float16* attn_l = f16base + foff; foff += (size_t)SEQ * HID;
  _Float16* ow_h   = f16base + foff; foff += (size_t)HID * HID;
  _Float16* ow_l   = f16base + foff; foff += (size_t)HID * HID;
  _Float16* Qhb    = f16base + foff; foff += (size_t)NHEAD * SEQ * HDIM;
  _Float16* Qlb    = f16base + foff; foff += (size_t)NHEAD * SEQ * HDIM;
  _Float16* Khb    = f16base + foff; foff += (size_t)NHEAD * SEQ * HDIM;
  _Float16* Klb    = f16base + foff; foff += (size_t)NHEAD * SEQ * HDIM;
  _Float16* Vthb   = f16base + foff; foff += (size_t)NHEAD * SEQ * HDIM;
  _Float16* Vtlb   = f16base + foff; foff += (size_t)NHEAD * SEQ * HDIM;

  k_split_f16<<<(QKVW * HID / 8 + 255) / 256, 256, 0, stream>>>(qkv_w, qkvw_h, qkvw_l, QKVW * HID / 8);
  k_split_f16<<<(HID * HID / 8 + 255) / 256, 256, 0, stream>>>(o_w, ow_h, ow_l, HID * HID / 8);

  k_rmsnorm<<<SEQ, 256, 0, stream>>>(x, anw, nullptr, nullptr, xn_h, xn_l);
  k_lin<<<dim3(QKVW / 128, SEQ / 128), 256, 0, stream>>>(xn_h, xn_l, qkvw_h, qkvw_l, nullptr, qkv, QKVW, HID);
  k_prep<<<dim3(NHEAD, SEQ / 64), 256, 0, stream>>>(qkv, Qhb, Qlb, Khb, Klb, Vthb, Vtlb);
  k_attn2<<<dim3(NHEAD, SEQ / 64), 256, 0, stream>>>(Qhb, Qlb, Khb, Klb, Vthb, Vtlb, attn_h, attn_l);
  k_lin<<<dim3(HID / 128, SEQ / 128), 256, 0, stream>>>(attn_h, attn_l, ow_h, ow_l, x, x1, HID, HID);
  k_rmsnorm<<<SEQ, 256, 0, stream>>>(x1, fnw, xn2, xn2_bf, nullptr, nullptr);
  k_router<<<SEQ, 64, 0, stream>>>(xn2, rw, tidx, tw);
  k_scan<<<1, 512, 0, stream>>>(tidx, slotk, perm, counts, out + (size_t)SEQ * HID);
  k_moe_gu<<<dim3(IDIM / 128, CAPE / 128, NEXP), 256, 0, stream>>>(xn2_bf, wg, wu, perm, counts, act_bf);
  k_moe_down<<<dim3(HID / 128, CAPE / 128, NEXP), 256, 0, stream>>>(act_bf, wd, counts, ybuf);
  k_combine<<<SEQ, 256, 0, stream>>>(x1, ybuf, tidx, tw, slotk, out);
}

// Round 2
// 830.661 us; speedup vs baseline: 1.0587x; 1.0587x over previous
//
#include <hip/hip_runtime.h>
#include <math.h>

#define SEQ   2048
#define HID   1024
#define NHEAD 16
#define HDIM  64
#define NEXP  8
#define IDIM  4096
#define CAPE  1024
#define QKVW  3072

typedef __bf16    bf16x8 __attribute__((ext_vector_type(8)));
typedef __bf16    bf16x4 __attribute__((ext_vector_type(4)));
typedef _Float16  f16x8  __attribute__((ext_vector_type(8)));
typedef _Float16  f16x4  __attribute__((ext_vector_type(4)));
typedef float     f32x4  __attribute__((ext_vector_type(4)));

__device__ __forceinline__ void gld16(const void* g, void* l) {
  __builtin_amdgcn_global_load_lds((const __attribute__((address_space(1))) void*)g,
                                   (__attribute__((address_space(3))) void*)l, 16, 0, 0);
}

__device__ __forceinline__ bf16x8 cvt_bf8(const float4 a, const float4 b) {
  bf16x8 o;
  o[0] = (__bf16)a.x; o[1] = (__bf16)a.y; o[2] = (__bf16)a.z; o[3] = (__bf16)a.w;
  o[4] = (__bf16)b.x; o[5] = (__bf16)b.y; o[6] = (__bf16)b.z; o[7] = (__bf16)b.w;
  return o;
}

// ---------------- RMSNorm: fp32 out (opt), bf16 out (opt), f16 hi/lo out (opt) ----------------
__global__ __launch_bounds__(256) void k_rmsnorm(const float* __restrict__ x,
                                                 const float* __restrict__ w,
                                                 float* __restrict__ out,
                                                 __bf16* __restrict__ out_bf,
                                                 _Float16* __restrict__ out_h,
                                                 _Float16* __restrict__ out_l) {
  const int row = blockIdx.x, t = threadIdx.x;
  float4 v = ((const float4*)(x + (size_t)row * HID))[t];
  float ss = v.x*v.x + v.y*v.y + v.z*v.z + v.w*v.w;
  #pragma unroll
  for (int off = 32; off; off >>= 1) ss += __shfl_down(ss, off);
  __shared__ float red[4];
  if ((t & 63) == 0) red[t >> 6] = ss;
  __syncthreads();
  const float inv = rsqrtf((red[0] + red[1] + red[2] + red[3]) * (1.0f / HID) + 1e-6f);
  float4 wv = ((const float4*)w)[t];
  float4 o = make_float4(v.x*inv*wv.x, v.y*inv*wv.y, v.z*inv*wv.z, v.w*inv*wv.w);
  if (out) ((float4*)(out + (size_t)row * HID))[t] = o;
  if (out_bf) {
    bf16x4 ob; ob[0] = (__bf16)o.x; ob[1] = (__bf16)o.y; ob[2] = (__bf16)o.z; ob[3] = (__bf16)o.w;
    *(bf16x4*)(out_bf + (size_t)row * HID + t * 4) = ob;
  }
  if (out_h) {
    f16x4 oh, ol;
    const float e0 = o.x, e1 = o.y, e2 = o.z, e3 = o.w;
    oh[0] = (_Float16)e0; ol[0] = (_Float16)(e0 - (float)oh[0]);
    oh[1] = (_Float16)e1; ol[1] = (_Float16)(e1 - (float)oh[1]);
    oh[2] = (_Float16)e2; ol[2] = (_Float16)(e2 - (float)oh[2]);
    oh[3] = (_Float16)e3; ol[3] = (_Float16)(e3 - (float)oh[3]);
    *(f16x4*)(out_h + (size_t)row * HID + t * 4) = oh;
    *(f16x4*)(out_l + (size_t)row * HID + t * 4) = ol;
  }
}

// ---------------- fp32 -> f16 hi/lo split ----------------
__global__ __launch_bounds__(256) void k_split_f16(const float* __restrict__ in,
                                                   _Float16* __restrict__ oh,
                                                   _Float16* __restrict__ ol,
                                                   long n8) {
  const long i = ((long)blockIdx.x * 256 + threadIdx.x);
  if (i >= n8) return;
  const float4 a = *(const float4*)(in + i * 8);
  const float4 b = *(const float4*)(in + i * 8 + 4);
  float e[8] = {a.x, a.y, a.z, a.w, b.x, b.y, b.z, b.w};
  f16x8 h, l;
  #pragma unroll
  for (int j = 0; j < 8; ++j) {
    h[j] = (_Float16)e[j];
    l[j] = (_Float16)(e[j] - (float)h[j]);
  }
  *(f16x8*)(oh + i * 8) = h;
  *(f16x8*)(ol + i * 8) = l;
}

// ---------------- split-f16 MFMA NT GEMM ----------------
__global__ __launch_bounds__(256, 2) void k_lin(const _Float16* __restrict__ Ah,
                                                const _Float16* __restrict__ Al,
                                                const _Float16* __restrict__ Bh,
                                                const _Float16* __restrict__ Bl,
                                                const float* __restrict__ res,
                                                float* __restrict__ C,
                                                int N, int Kd) {
  const int m0 = blockIdx.y * 128, n0 = blockIdx.x * 128;
  __shared__ __align__(16) _Float16 Ash[128 * 32];
  __shared__ __align__(16) _Float16 Asl[128 * 32];
  __shared__ __align__(16) _Float16 Bsh[128 * 32];
  __shared__ __align__(16) _Float16 Bsl[128 * 32];
  const int t = threadIdx.x, lane = t & 63, w = t >> 6;
  const int wr = w & 1, wc = w >> 1;
  const int sr = t >> 2, sk = (t & 3) * 8;
  const size_t a0 = (size_t)(m0 + sr) * Kd, a1 = (size_t)(m0 + 64 + sr) * Kd;
  const size_t b0 = (size_t)(n0 + sr) * Kd, b1 = (size_t)(n0 + 64 + sr) * Kd;
  f32x4 acc[4][4];
  #pragma unroll
  for (int i = 0; i < 4; ++i)
    #pragma unroll
    for (int j = 0; j < 4; ++j) acc[i][j] = (f32x4)(0.f);

  for (int kk = 0; kk < Kd; kk += 32) {
    gld16(Ah + a0 + kk + sk, Ash + w * 512);
    gld16(Ah + a1 + kk + sk, Ash + 2048 + w * 512);
    gld16(Al + a0 + kk + sk, Asl + w * 512);
    gld16(Al + a1 + kk + sk, Asl + 2048 + w * 512);
    gld16(Bh + b0 + kk + sk, Bsh + w * 512);
    gld16(Bh + b1 + kk + sk, Bsh + 2048 + w * 512);
    gld16(Bl + b0 + kk + sk, Bsl + w * 512);
    gld16(Bl + b1 + kk + sk, Bsl + 2048 + w * 512);
    __syncthreads();
    const int fo = (lane & 15) * 32 + (lane >> 4) * 8;
    f16x8 ah[4], al[4], bh[4], bl[4];
    #pragma unroll
    for (int i = 0; i < 4; ++i) {
      ah[i] = *(const f16x8*)&Ash[(wr * 64 + i * 16) * 32 + fo];
      al[i] = *(const f16x8*)&Asl[(wr * 64 + i * 16) * 32 + fo];
      bh[i] = *(const f16x8*)&Bsh[(wc * 64 + i * 16) * 32 + fo];
      bl[i] = *(const f16x8*)&Bsl[(wc * 64 + i * 16) * 32 + fo];
    }
    #pragma unroll
    for (int i = 0; i < 4; ++i)
      #pragma unroll
      for (int j = 0; j < 4; ++j) {
        acc[i][j] = __builtin_amdgcn_mfma_f32_16x16x32_f16(al[i], bh[j], acc[i][j], 0, 0, 0);
        acc[i][j] = __builtin_amdgcn_mfma_f32_16x16x32_f16(ah[i], bl[j], acc[i][j], 0, 0, 0);
        acc[i][j] = __builtin_amdgcn_mfma_f32_16x16x32_f16(ah[i], bh[j], acc[i][j], 0, 0, 0);
      }
    __syncthreads();
  }
  const int cb = lane & 15, rb = (lane >> 4) * 4;
  #pragma unroll
  for (int i = 0; i < 4; ++i)
    #pragma unroll
    for (int r = 0; r < 4; ++r) {
      const int rr = m0 + wr * 64 + i * 16 + rb + r;
      #pragma unroll
      for (int j = 0; j < 4; ++j) {
        const int cc = n0 + wc * 64 + j * 16 + cb;
        float v = acc[i][j][r];
        if (res) v += res[(size_t)rr * N + cc];
        C[(size_t)rr * N + cc] = v;
      }
    }
}

// ---------------- prep: RoPE + q-scale + f16 hi/lo split of Q,K; V transpose+split ----------------
__global__ __launch_bounds__(256) void k_prep(const float* __restrict__ qkv,
                                              _Float16* __restrict__ Qh, _Float16* __restrict__ Ql,
                                              _Float16* __restrict__ Kh, _Float16* __restrict__ Kl,
                                              _Float16* __restrict__ Vth, _Float16* __restrict__ Vtl) {
  const int h = blockIdx.x, s0 = blockIdx.y * 64;
  const int t = threadIdx.x;
  const int sl = t >> 2, qd = t & 3;
  const int s = s0 + sl;
  const float* base = qkv + (size_t)s * QKVW + h * HDIM;
  __shared__ float vt[64][65];

  {
    const float* vb = base + 2 * HID + qd * 16;
    #pragma unroll
    for (int c = 0; c < 4; ++c) {
      float4 v = *(const float4*)(vb + c * 4);
      vt[sl][qd * 16 + c * 4 + 0] = v.x;
      vt[sl][qd * 16 + c * 4 + 1] = v.y;
      vt[sl][qd * 16 + c * 4 + 2] = v.z;
      vt[sl][qd * 16 + c * 4 + 3] = v.w;
    }
  }

  const int d0 = qd * 8;
  const float LOG10000 = 9.210340371976184f;
  float cv[8], sv[8];
  #pragma unroll
  for (int i = 0; i < 8; ++i) {
    const float ang = (float)s * expf(-(float)(d0 + i) * (1.0f / 32.0f) * LOG10000);
    sincosf(ang, &sv[i], &cv[i]);
  }
  float qa[8], qb[8], ka[8], kb[8];
  {
    float4 x0 = *(const float4*)(base + d0), x1 = *(const float4*)(base + d0 + 4);
    float4 y0 = *(const float4*)(base + d0 + 32), y1 = *(const float4*)(base + d0 + 36);
    qa[0]=x0.x; qa[1]=x0.y; qa[2]=x0.z; qa[3]=x0.w; qa[4]=x1.x; qa[5]=x1.y; qa[6]=x1.z; qa[7]=x1.w;
    qb[0]=y0.x; qb[1]=y0.y; qb[2]=y0.z; qb[3]=y0.w; qb[4]=y1.x; qb[5]=y1.y; qb[6]=y1.z; qb[7]=y1.w;
    const float* kbase = base + HID;
    float4 z0 = *(const float4*)(kbase + d0), z1 = *(const float4*)(kbase + d0 + 4);
    float4 w0 = *(const float4*)(kbase + d0 + 32), w1 = *(const float4*)(kbase + d0 + 36);
    ka[0]=z0.x; ka[1]=z0.y; ka[2]=z0.z; ka[3]=z0.w; ka[4]=z1.x; ka[5]=z1.y; ka[6]=z1.z; ka[7]=z1.w;
    kb[0]=w0.x; kb[1]=w0.y; kb[2]=w0.z; kb[3]=w0.w; kb[4]=w1.x; kb[5]=w1.y; kb[6]=w1.z; kb[7]=w1.w;
  }
  f16x8 qh_a, ql_a, qh_b, ql_b, kh_a, kl_a, kh_b, kl_b;
  #pragma unroll
  for (int i = 0; i < 8; ++i) {
    const float q1 = (qa[i] * cv[i] - qb[i] * sv[i]) * 0.125f;
    const float q2 = (qb[i] * cv[i] + qa[i] * sv[i]) * 0.125f;
    const float k1 = ka[i] * cv[i] - kb[i] * sv[i];
    const float k2 = kb[i] * cv[i] + ka[i] * sv[i];
    qh_a[i] = (_Float16)q1; ql_a[i] = (_Float16)(q1 - (float)qh_a[i]);
    qh_b[i] = (_Float16)q2; ql_b[i] = (_Float16)(q2 - (float)qh_b[i]);
    kh_a[i] = (_Float16)k1; kl_a[i] = (_Float16)(k1 - (float)kh_a[i]);
    kh_b[i] = (_Float16)k2; kl_b[i] = (_Float16)(k2 - (float)kh_b[i]);
  }
  const size_t qko = ((size_t)h * SEQ + s) * 64;
  *(f16x8*)(Qh + qko + d0) = qh_a;      *(f16x8*)(Qh + qko + d0 + 32) = qh_b;
  *(f16x8*)(Ql + qko + d0) = ql_a;      *(f16x8*)(Ql + qko + d0 + 32) = ql_b;
  *(f16x8*)(Kh + qko + d0) = kh_a;      *(f16x8*)(Kh + qko + d0 + 32) = kh_b;
  *(f16x8*)(Kl + qko + d0) = kl_a;      *(f16x8*)(Kl + qko + d0 + 32) = kl_b;

  __syncthreads();
  {
    const int d = t >> 2, sc = (t & 3) * 16;
    f16x8 vh0, vl0, vh1, vl1;
    #pragma unroll
    for (int j = 0; j < 8; ++j) {
      const float v = vt[sc + j][d];
      vh0[j] = (_Float16)v; vl0[j] = (_Float16)(v - (float)vh0[j]);
    }
    #pragma unroll
    for (int j = 0; j < 8; ++j) {
      const float v = vt[sc + 8 + j][d];
      vh1[j] = (_Float16)v; vl1[j] = (_Float16)(v - (float)vh1[j]);
    }
    const size_t vo = ((size_t)h * HDIM + d) * SEQ + s0 + sc;
    *(f16x8*)(Vth + vo) = vh0; *(f16x8*)(Vth + vo + 8) = vh1;
    *(f16x8*)(Vtl + vo) = vl0; *(f16x8*)(Vtl + vo + 8) = vl1;
  }
}

// ---------------- MFMA flash attention, split-f16 (fp32-equivalent) ----------------
__global__ __launch_bounds__(256) void k_attn2(
    const _Float16* __restrict__ Qh, const _Float16* __restrict__ Ql,
    const _Float16* __restrict__ Kh, const _Float16* __restrict__ Kl,
    const _Float16* __restrict__ Vth, const _Float16* __restrict__ Vtl,
    _Float16* __restrict__ attn_h, _Float16* __restrict__ attn_l) {
  const int h = blockIdx.x;
  const int qt = (int)gridDim.y - 1 - (int)blockIdx.y;   // heavy tiles first
  const int t = threadIdx.x, lane = t & 63, w = t >> 6;
  const int m_ = lane & 15, quad = lane >> 4;

  __shared__ __align__(16) _Float16 Ksh[2][64][32];
  __shared__ __align__(16) _Float16 Ksl[2][64][32];
  __shared__ __align__(16) _Float16 Vsh[4][64][16];
  __shared__ __align__(16) _Float16 Vsl[4][64][16];
  __shared__ __align__(16) _Float16 Ph[4][16][72];
  __shared__ __align__(16) _Float16 Pl[4][16][72];

  const int q0 = qt * 64 + w * 16;
  const _Float16* qbh = Qh + ((size_t)h * SEQ + q0 + m_) * 64 + quad * 8;
  const _Float16* qbl = Ql + ((size_t)h * SEQ + q0 + m_) * 64 + quad * 8;
  const f16x8 qh0 = *(const f16x8*)(qbh);
  const f16x8 qh1 = *(const f16x8*)(qbh + 32);
  const f16x8 ql0 = *(const f16x8*)(qbl);
  const f16x8 ql1 = *(const f16x8*)(qbl + 32);

  f32x4 o[4];
  #pragma unroll
  for (int nt = 0; nt < 4; ++nt) o[nt] = (f32x4)(0.f);
  float m_r[4] = {-1e30f, -1e30f, -1e30f, -1e30f};
  float l_r[4] = {0.f, 0.f, 0.f, 0.f};

  for (int kt = 0; kt <= qt; ++kt) {
    if (w == 0) {
      #pragma unroll
      for (int c = 0; c < 2; ++c)
        #pragma unroll
        for (int kb = 0; kb < 4; ++kb)
          gld16(Kh + ((size_t)h * SEQ + kt * 64 + kb * 16 + (lane >> 2)) * 64 + c * 32 + (lane & 3) * 8,
                &Ksh[c][kb * 16][0]);
    } else if (w == 1) {
      #pragma unroll
      for (int c = 0; c < 2; ++c)
        #pragma unroll
        for (int kb = 0; kb < 4; ++kb)
          gld16(Kl + ((size_t)h * SEQ + kt * 64 + kb * 16 + (lane >> 2)) * 64 + c * 32 + (lane & 3) * 8,
                &Ksl[c][kb * 16][0]);
    } else if (w == 2) {
      #pragma unroll
      for (int g = 0; g < 4; ++g)
        #pragma unroll
        for (int hd = 0; hd < 2; ++hd)
          gld16(Vth + ((size_t)h * HDIM + hd * 32 + (lane >> 1)) * SEQ + kt * 64 + g * 16 + (lane & 1) * 8,
                &Vsh[g][hd * 32][0]);
    } else {
      #pragma unroll
      for (int g = 0; g < 4; ++g)
        #pragma unroll
        for (int hd = 0; hd < 2; ++hd)
          gld16(Vtl + ((size_t)h * HDIM + hd * 32 + (lane >> 1)) * SEQ + kt * 64 + g * 16 + (lane & 1) * 8,
                &Vsl[g][hd * 32][0]);
    }
    __syncthreads();

    // ---- S = Q K^T ----
    f32x4 s4[4];
    #pragma unroll
    for (int nt = 0; nt < 4; ++nt) s4[nt] = (f32x4)(0.f);
    __builtin_amdgcn_s_setprio(1);
    #pragma unroll
    for (int c = 0; c < 2; ++c) {
      const f16x8 qhc = c ? qh1 : qh0;
      const f16x8 qlc = c ? ql1 : ql0;
      #pragma unroll
      for (int nt = 0; nt < 4; ++nt) {
        const f16x8 kh8 = *(const f16x8*)&Ksh[c][nt * 16 + m_][quad * 8];
        const f16x8 kl8 = *(const f16x8*)&Ksl[c][nt * 16 + m_][quad * 8];
        s4[nt] = __builtin_amdgcn_mfma_f32_16x16x32_f16(qlc, kh8, s4[nt], 0, 0, 0);
        s4[nt] = __builtin_amdgcn_mfma_f32_16x16x32_f16(qhc, kl8, s4[nt], 0, 0, 0);
        s4[nt] = __builtin_amdgcn_mfma_f32_16x16x32_f16(qhc, kh8, s4[nt], 0, 0, 0);
      }
    }
    __builtin_amdgcn_s_setprio(0);
    if (kt == qt) {
      #pragma unroll
      for (int nt = 0; nt < 4; ++nt)
        #pragma unroll
        for (int r = 0; r < 4; ++r)
          if (nt * 16 + m_ > w * 16 + quad * 4 + r) s4[nt][r] = -1e30f;
    }
    float mx[4];
    #pragma unroll
    for (int r = 0; r < 4; ++r)
      mx[r] = fmaxf(fmaxf(s4[0][r], s4[1][r]), fmaxf(s4[2][r], s4[3][r]));
    #pragma unroll
    for (int msk = 1; msk < 16; msk <<= 1)
      #pragma unroll
      for (int r = 0; r < 4; ++r) mx[r] = fmaxf(mx[r], __shfl_xor(mx[r], msk));
    float al[4];
    #pragma unroll
    for (int r = 0; r < 4; ++r) {
      const float mn = fmaxf(m_r[r], mx[r]);
      al[r] = expf(m_r[r] - mn);
      m_r[r] = mn;
    }
    float rs[4] = {0.f, 0.f, 0.f, 0.f};
    #pragma unroll
    for (int nt = 0; nt < 4; ++nt) {
      #pragma unroll
      for (int r = 0; r < 4; ++r) {
        const float p = expf(s4[nt][r] - m_r[r]);
        rs[r] += p;
        const _Float16 ph = (_Float16)p;
        Ph[w][quad * 4 + r][nt * 16 + m_] = ph;
        Pl[w][quad * 4 + r][nt * 16 + m_] = (_Float16)(p - (float)ph);
      }
    }
    #pragma unroll
    for (int msk = 1; msk < 16; msk <<= 1)
      #pragma unroll
      for (int r = 0; r < 4; ++r) rs[r] += __shfl_xor(rs[r], msk);
    #pragma unroll
    for (int r = 0; r < 4; ++r) l_r[r] = l_r[r] * al[r] + rs[r];
    #pragma unroll
    for (int nt = 0; nt < 4; ++nt)
      #pragma unroll
      for (int r = 0; r < 4; ++r) o[nt][r] *= al[r];

    // ---- O += P V ----
    __builtin_amdgcn_s_setprio(1);
    #pragma unroll
    for (int c = 0; c < 2; ++c) {
      const f16x8 pah = *(const f16x8*)&Ph[w][m_][c * 32 + quad * 8];
      const f16x8 pal = *(const f16x8*)&Pl[w][m_][c * 32 + quad * 8];
      #pragma unroll
      for (int nt = 0; nt < 4; ++nt) {
        const f16x8 vh8 = *(const f16x8*)&Vsh[c * 2 + (quad >> 1)][nt * 16 + m_][(quad & 1) * 8];
        const f16x8 vl8 = *(const f16x8*)&Vsl[c * 2 + (quad >> 1)][nt * 16 + m_][(quad & 1) * 8];
        o[nt] = __builtin_amdgcn_mfma_f32_16x16x32_f16(pal, vh8, o[nt], 0, 0, 0);
        o[nt] = __builtin_amdgcn_mfma_f32_16x16x32_f16(pah, vl8, o[nt], 0, 0, 0);
        o[nt] = __builtin_amdgcn_mfma_f32_16x16x32_f16(pah, vh8, o[nt], 0, 0, 0);
      }
    }
    __builtin_amdgcn_s_setprio(0);
    __syncthreads();
  }

  float inv[4];
  #pragma unroll
  for (int r = 0; r < 4; ++r) inv[r] = 1.0f / l_r[r];
  #pragma unroll
  for (int nt = 0; nt < 4; ++nt)
    #pragma unroll
    for (int r = 0; r < 4; ++r) {
      const float v = o[nt][r] * inv[r];
      const _Float16 hi = (_Float16)v;
      const size_t idx = ((size_t)(q0 + quad * 4 + r)) * HID + h * HDIM + nt * 16 + m_;
      attn_h[idx] = hi;
      attn_l[idx] = (_Float16)(v - (float)hi);
    }
}

// ---------------- router ----------------
__global__ __launch_bounds__(64) void k_router(const float* __restrict__ xn2,
                                               const float* __restrict__ rw,
                                               int* __restrict__ tidx,
                                               float* __restrict__ tw) {
  const int n = blockIdx.x, lane = threadIdx.x;
  float lg[8] = {0.f,0.f,0.f,0.f,0.f,0.f,0.f,0.f};
  #pragma unroll
  for (int i = 0; i < 4; ++i) {
    float4 xv = ((const float4*)(xn2 + (size_t)n * HID))[lane + 64 * i];
    #pragma unroll
    for (int e = 0; e < 8; ++e) {
      float4 wv = ((const float4*)(rw + (size_t)e * HID))[lane + 64 * i];
      lg[e] += xv.x*wv.x + xv.y*wv.y + xv.z*wv.z + xv.w*wv.w;
    }
  }
  #pragma unroll
  for (int e = 0; e < 8; ++e) {
    #pragma unroll
    for (int off = 32; off; off >>= 1) lg[e] += __shfl_xor(lg[e], off);
  }
  if (lane == 0) {
    int e1 = 0; float l1 = lg[0];
    #pragma unroll
    for (int e = 1; e < 8; ++e) if (lg[e] > l1) { l1 = lg[e]; e1 = e; }
    int e2 = -1; float l2 = -INFINITY;
    #pragma unroll
    for (int e = 0; e < 8; ++e) if (e != e1 && lg[e] > l2) { l2 = lg[e]; e2 = e; }
    const float w1 = 1.0f / (1.0f + expf(l2 - l1));
    tidx[n * 2] = e1; tidx[n * 2 + 1] = e2;
    tw[n * 2] = w1;  tw[n * 2 + 1] = 1.0f - w1;
  }
}

// ---------------- capacity scan + aux loss ----------------
__global__ __launch_bounds__(512) void k_scan(const int* __restrict__ tidx,
                                              int* __restrict__ slotk,
                                              int* __restrict__ perm,
                                              int* __restrict__ counts,
                                              float* __restrict__ aux_out) {
  const int t = threadIdx.x;
  const int e = t >> 6, lane = t & 63;
  __shared__ int cls[8];
  int offset = 0;
  for (int chunk = 0; chunk < SEQ / 64; ++chunk) {
    const int n = chunk * 64 + lane;
    const int i0 = tidx[n * 2], i1 = tidx[n * 2 + 1];
    const bool bit = (i0 == e) || (i1 == e);
    const unsigned long long mask = __ballot(bit);
    const int pos = offset + __popcll(mask & ((1ull << lane) - 1ull));
    if (bit) {
      const int kk = (i0 == e) ? 0 : 1;
      slotk[n * 2 + kk] = pos;
      if (pos < CAPE) perm[e * CAPE + pos] = n;
    }
    offset += __popcll(mask);
  }
  if (lane == 0) { counts[e] = offset; cls[e] = offset; }
  __syncthreads();
  if (t == 0) {
    float mean = 0.f;
    for (int i = 0; i < 8; ++i) mean += (float)cls[i];
    mean /= (8.0f * (float)SEQ);
    float var = 0.f;
    for (int i = 0; i < 8; ++i) {
      const float f = (float)cls[i] / (float)SEQ;
      var += (f - mean) * (f - mean);
    }
    var /= 7.0f;
    aux_out[0] = var * 8.0f;
  }
}

// ---------------- MoE gate/up: fp32 B staged via gld16 (swizzled), consumer-side bf16 cvt ----------------
// Swizzle (rule #21): linear LDS dest, inverse-permuted global source col, XOR on read.
// Physical (row, slot s) holds logical (row, s ^ (row&7)); slot = 16B/4-float unit.
__global__ __launch_bounds__(256, 2) void k_moe_gu(const __bf16* __restrict__ X,
                                                   const float* __restrict__ Wg,
                                                   const float* __restrict__ Wu,
                                                   const int* __restrict__ perm,
                                                   const int* __restrict__ counts,
                                                   __bf16* __restrict__ act) {
  const int e = blockIdx.z;
  const int rows = min(counts[e], CAPE);
  const int m0 = blockIdx.y * 128;
  if (m0 >= rows) return;
  const int n0 = blockIdx.x * 128;
  __shared__ __align__(16) __bf16 As[128 * 32];    // 8 KB
  __shared__ __align__(16) float  Bgf[128 * 32];   // 16 KB
  __shared__ __align__(16) float  Buf[128 * 32];   // 16 KB
  const int t = threadIdx.x;
  const int lane = t & 63, w = t >> 6;
  const int wr = w & 1, wc = w >> 1;
  const int sr = t >> 2, sk = (t & 3) * 8;
  const int gr0 = m0 + sr, gr1 = m0 + 64 + sr;
  const size_t arow0 = (size_t)((gr0 < rows) ? perm[e * CAPE + gr0] : 0) * HID;
  const size_t arow1 = (size_t)((gr1 < rows) ? perm[e * CAPE + gr1] : 0) * HID;
  const float* gB = Wg + (size_t)e * IDIM * HID;
  const float* uB = Wu + (size_t)e * IDIM * HID;
  // B staging: pass p covers rows p*32+(t>>3); source col pre-swizzled so linear dest lands swizzled
  const int brow = t >> 3;                          // 0..31
  const int scol = ((t ^ (t >> 3)) & 7) * 4;        // (slot ^ (row&7)) * 4 floats
  const size_t bsrc = (size_t)(n0 + brow) * HID + scol;
  f32x4 accg[4][4], accu[4][4];
  #pragma unroll
  for (int i = 0; i < 4; ++i)
    #pragma unroll
    for (int j = 0; j < 4; ++j) { accg[i][j] = (f32x4)(0.f); accu[i][j] = (f32x4)(0.f); }

  for (int kk = 0; kk < HID; kk += 32) {
    gld16(X + arow0 + kk + sk, As + w * 512);
    gld16(X + arow1 + kk + sk, As + 2048 + w * 512);
    #pragma unroll
    for (int p = 0; p < 4; ++p) {
      gld16(gB + bsrc + (size_t)p * 32 * HID + kk, Bgf + p * 1024 + w * 256);
      gld16(uB + bsrc + (size_t)p * 32 * HID + kk, Buf + p * 1024 + w * 256);
    }
    __syncthreads();
    const int fo = (lane & 15) * 32 + (lane >> 4) * 8;
    const int q2 = (lane >> 4) * 2;     // logical base slot (0,2,4,6)
    const int rx = lane & 7;            // row&7 for all frag rows
    const int p0 = ((q2) ^ rx) * 4, p1 = ((q2 | 1) ^ rx) * 4;
    bf16x8 a[4], bg[4], bu[4];
    #pragma unroll
    for (int i = 0; i < 4; ++i) {
      a[i]  = *(const bf16x8*)&As[(wr * 64 + i * 16) * 32 + fo];
      const int R = (wc * 64 + i * 16 + (lane & 15)) * 32;
      const float4 g0 = *(const float4*)&Bgf[R + p0];
      const float4 g1 = *(const float4*)&Bgf[R + p1];
      const float4 u0 = *(const float4*)&Buf[R + p0];
      const float4 u1 = *(const float4*)&Buf[R + p1];
      bg[i] = cvt_bf8(g0, g1);
      bu[i] = cvt_bf8(u0, u1);
    }
    #pragma unroll
    for (int i = 0; i < 4; ++i)
      #pragma unroll
      for (int j = 0; j < 4; ++j) {
        accg[i][j] = __builtin_amdgcn_mfma_f32_16x16x32_bf16(a[i], bg[j], accg[i][j], 0, 0, 0);
        accu[i][j] = __builtin_amdgcn_mfma_f32_16x16x32_bf16(a[i], bu[j], accu[i][j], 0, 0, 0);
      }
    __syncthreads();
  }
  const int cb = lane & 15, rb = (lane >> 4) * 4;
  #pragma unroll
  for (int i = 0; i < 4; ++i)
    #pragma unroll
    for (int r = 0; r < 4; ++r) {
      const int rr = m0 + wr * 64 + i * 16 + rb + r;
      if (rr < rows) {
        #pragma unroll
        for (int j = 0; j < 4; ++j) {
          const float g = accg[i][j][r], u = accu[i][j][r];
          const float v = g / (1.f + expf(-g)) * u;
          act[((size_t)e * CAPE + rr) * IDIM + n0 + wc * 64 + j * 16 + cb] = (__bf16)v;
        }
      }
    }
}

// ---------------- MoE down: fp32 B staged via gld16 (swizzled), consumer-side bf16 cvt ----------------
__global__ __launch_bounds__(256, 2) void k_moe_down(const __bf16* __restrict__ act,
                                                     const float* __restrict__ Wd,
                                                     const int* __restrict__ counts,
                                                     float* __restrict__ y) {
  const int e = blockIdx.z;
  const int rows = min(counts[e], CAPE);
  const int m0 = blockIdx.y * 128;
  if (m0 >= rows) return;
  const int n0 = blockIdx.x * 128;
  __shared__ __align__(16) __bf16 As[128 * 32];    // 8 KB
  __shared__ __align__(16) float  Bf[128 * 32];    // 16 KB
  const int t = threadIdx.x;
  const int lane = t & 63, w = t >> 6;
  const int wr = w & 1, wc = w >> 1;
  const int sr = t >> 2;
  const int sk = (t & 3) * 8;
  const __bf16* Ab = act + ((size_t)e * CAPE) * IDIM;
  const float* Bb = Wd + (size_t)e * HID * IDIM;
  const size_t arow0 = (size_t)(m0 + sr) * IDIM, arow1 = (size_t)(m0 + 64 + sr) * IDIM;
  const int brow = t >> 3;
  const int scol = ((t ^ (t >> 3)) & 7) * 4;
  const size_t bsrc = (size_t)(n0 + brow) * IDIM + scol;
  f32x4 acc[4][4];
  #pragma unroll
  for (int i = 0; i < 4; ++i)
    #pragma unroll
    for (int j = 0; j < 4; ++j) acc[i][j] = (f32x4)(0.f);

  for (int kk = 0; kk < IDIM; kk += 32) {
    gld16(Ab + arow0 + kk + sk, As + w * 512);
    gld16(Ab + arow1 + kk + sk, As + 2048 + w * 512);
    #pragma unroll
    for (int p = 0; p < 4; ++p)
      gld16(Bb + bsrc + (size_t)p * 32 * IDIM + kk, Bf + p * 1024 + w * 256);
    __syncthreads();
    const int fo = (lane & 15) * 32 + (lane >> 4) * 8;
    const int q2 = (lane >> 4) * 2;
    const int rx = lane & 7;
    const int p0 = ((q2) ^ rx) * 4, p1 = ((q2 | 1) ^ rx) * 4;
    bf16x8 a[4], b[4];
    #pragma unroll
    for (int i = 0; i < 4; ++i) {
      a[i] = *(const bf16x8*)&As[(wr * 64 + i * 16) * 32 + fo];
      const int R = (wc * 64 + i * 16 + (lane & 15)) * 32;
      const float4 b0 = *(const float4*)&Bf[R + p0];
      const float4 b1 = *(const float4*)&Bf[R + p1];
      b[i] = cvt_bf8(b0, b1);
    }
    #pragma unroll
    for (int i = 0; i < 4; ++i)
      #pragma unroll
      for (int j = 0; j < 4; ++j)
        acc[i][j] = __builtin_amdgcn_mfma_f32_16x16x32_bf16(a[i], b[j], acc[i][j], 0, 0, 0);
    __syncthreads();
  }
  const int cb = lane & 15, rb = (lane >> 4) * 4;
  #pragma unroll
  for (int i = 0; i < 4; ++i)
    #pragma unroll
    for (int r = 0; r < 4; ++r) {
      const int rr = m0 + wr * 64 + i * 16 + rb + r;
      if (rr < rows) {
        #pragma unroll
        for (int j = 0; j < 4; ++j)
          y[((size_t)e * CAPE + rr) * HID + n0 + wc * 64 + j * 16 + cb] = acc[i][j][r];
      }
    }
}

// ---------------- combine ----------------
__global__ __launch_bounds__(256) void k_combine(const float* __restrict__ x1,
                                                 const float* __restrict__ y,
                                                 const int* __restrict__ tidx,
                                                 const float* __restrict__ tw,
                                                 const int* __restrict__ slotk,
                                                 float* __restrict__ out) {
  const int n = blockIdx.x, t = threadIdx.x;
  float4 acc = ((const float4*)(x1 + (size_t)n * HID))[t];
  #pragma unroll
  for (int k = 0; k < 2; ++k) {
    const int slot = slotk[n * 2 + k];
    if (slot < CAPE) {
      const int e = tidx[n * 2 + k];
      const float w = tw[n * 2 + k];
      float4 v = ((const float4*)(y + ((size_t)e * CAPE + slot) * HID))[t];
      acc.x += w * v.x; acc.y += w * v.y; acc.z += w * v.z; acc.w += w * v.w;
    }
  }
  ((float4*)(out + (size_t)n * HID))[t] = acc;
}

extern "C" void kernel_launch(void* const* d_in, const int* in_sizes, int n_in,
                              void* d_out, int out_size, void* d_ws, size_t ws_size,
                              hipStream_t stream) {
  const float* x     = (const float*)d_in[0];
  const float* anw   = (const float*)d_in[1];
  const float* qkv_w = (const float*)d_in[2];
  const float* o_w   = (const float*)d_in[3];
  const float* fnw   = (const float*)d_in[4];
  const float* rw    = (const float*)d_in[5];
  const float* wg    = (const float*)d_in[6];
  const float* wu    = (const float*)d_in[7];
  const float* wd    = (const float*)d_in[8];
  (void)in_sizes; (void)n_in; (void)out_size; (void)ws_size;
  float* out = (float*)d_out;

  float* ws = (float*)d_ws;
  size_t off = 0;
  float* qkv  = ws + off; off += (size_t)SEQ * QKVW;
  float* x1   = ws + off; off += (size_t)SEQ * HID;
  float* xn2  = ws + off; off += (size_t)SEQ * HID;
  float* ybuf = ws + off; off += (size_t)NEXP * CAPE * HID;
  float* tw   = ws + off; off += SEQ * 2;
  int* tidx   = (int*)(ws + off); off += SEQ * 2;
  int* slotk  = (int*)(ws + off); off += SEQ * 2;
  int* perm   = (int*)(ws + off); off += NEXP * CAPE;
  int* counts = (int*)(ws + off); off += 16;
  // 2-byte element region
  __bf16* bfbase = (__bf16*)(ws + off);
  size_t boff = 0;
  __bf16* xn2_bf = bfbase + boff; boff += (size_t)SEQ * HID;
  __bf16* act_bf = bfbase + boff; boff += (size_t)NEXP * CAPE * IDIM;
  _Float16* f16base = (_Float16*)(bfbase + boff);
  size_t foff = 0;
  _Float16* xn_h   = f16base + foff; foff += (size_t)SEQ * HID;
  _Float16* xn_l   = f16base + foff; foff += (size_t)SEQ * HID;
  _Float16* qkvw_h = f16base + foff; foff += (size_t)QKVW * HID;
  _Float16* qkvw_l = f16base + foff; foff += (size_t)QKVW * HID;
  _Float16* attn_h = f16base + foff; foff += (size_t)SEQ * HID;
  _Float16* attn_l = f16base + foff; foff += (size_t)SEQ * HID;
  _Float16* ow_h   = f16base + foff; foff += (size_t)HID * HID;
  _Float16* ow_l   = f16base + foff; foff += (size_t)HID * HID;
  _Float16* Qhb    = f16base + foff; foff += (size_t)NHEAD * SEQ * HDIM;
  _Float16* Qlb    = f16base + foff; foff += (size_t)NHEAD * SEQ * HDIM;
  _Float16* Khb    = f16base + foff; foff += (size_t)NHEAD * SEQ * HDIM;
  _Float16* Klb    = f16base + foff; foff += (size_t)NHEAD * SEQ * HDIM;
  _Float16* Vthb   = f16base + foff; foff += (size_t)NHEAD * SEQ * HDIM;
  _Float16* Vtlb   = f16base + foff; foff += (size_t)NHEAD * SEQ * HDIM;

  k_split_f16<<<(QKVW * HID / 8 + 255) / 256, 256, 0, stream>>>(qkv_w, qkvw_h, qkvw_l, QKVW * HID / 8);
  k_split_f16<<<(HID * HID / 8 + 255) / 256, 256, 0, stream>>>(o_w, ow_h, ow_l, HID * HID / 8);

  k_rmsnorm<<<SEQ, 256, 0, stream>>>(x, anw, nullptr, nullptr, xn_h, xn_l);
  k_lin<<<dim3(QKVW / 128, SEQ / 128), 256, 0, stream>>>(xn_h, xn_l, qkvw_h, qkvw_l, nullptr, qkv, QKVW, HID);
  k_prep<<<dim3(NHEAD, SEQ / 64), 256, 0, stream>>>(qkv, Qhb, Qlb, Khb, Klb, Vthb, Vtlb);
  k_attn2<<<dim3(NHEAD, SEQ / 64), 256, 0, stream>>>(Qhb, Qlb, Khb, Klb, Vthb, Vtlb, attn_h, attn_l);
  k_lin<<<dim3(HID / 128, SEQ / 128), 256, 0, stream>>>(attn_h, attn_l, ow_h, ow_l, x, x1, HID, HID);
  k_rmsnorm<<<SEQ, 256, 0, stream>>>(x1, fnw, xn2, xn2_bf, nullptr, nullptr);
  k_router<<<SEQ, 64, 0, stream>>>(xn2, rw, tidx, tw);
  k_scan<<<1, 512, 0, stream>>>(tidx, slotk, perm, counts, out + (size_t)SEQ * HID);
  k_moe_gu<<<dim3(IDIM / 128, CAPE / 128, NEXP), 256, 0, stream>>>(xn2_bf, wg, wu, perm, counts, act_bf);
  k_moe_down<<<dim3(HID / 128, CAPE / 128, NEXP), 256, 0, stream>>>(act_bf, wd, counts, ybuf);
  k_combine<<<SEQ, 256, 0, stream>>>(x1, ybuf, tidx, tw, slotk, out);
}